// Round 4
// baseline (1134.643 us; speedup 1.0000x reference)
//
#include <hip/hip_runtime.h>
#include <math.h>

// Rod_Block: N=8, C_IN=64, C_OUT=128, G=4, CG=16, K=3, P=9, PAD=1, H=W=64.
// All tensors fp32. Padded spatial 66x66.
// Round-19: single persistent kernel. The 4-dispatch pipeline had ~60us of
// inter-dispatch overhead (~15us/boundary; kernel sum ~130us vs wall 193us).
// Fuse pool -> gain -> xsproj -> dwsamp into ONE 2048-block kernel with
// device-scope grid barriers (hierarchical atomics + threadfence for
// cross-XCD L2 visibility). Phase bodies verbatim from R17/R18 (controls).
// Residency proof: LDS 11264B -> 14 blk/CU; launch_bounds(128,4) -> VGPR<=128
// -> >=8 blk/CU; need 2048/256 = 8 blk/CU. 14 >= 8, all blocks co-resident.

#define NBLK 2048

// Wave-local LDS fence: orders this wave's ds writes before its later ds
// reads. No inter-wave rendezvous, no vmcnt drain. "memory" clobber blocks
// compiler motion across the phase boundary.
#define WAVE_FENCE() asm volatile("s_waitcnt lgkmcnt(0)" ::: "memory")

// ---- init: zero the sync area (102 ints used, 128 zeroed) ----
__global__ __launch_bounds__(128) void k_init(int* sync) {
    sync[threadIdx.x] = 0;
}

// Grid barrier: 32 group counters (64 blocks each) + root + release flag.
// Writer side: __syncthreads drains this block's stores; thread0 threadfence
// (agent scope => L2 writeback) then arrives. Release flag set only after all
// 2048 arrivals => all data at the coherent point. Reader side: acquire load
// + threadfence (L2 invalidate) before touching produced data.
__device__ __forceinline__ void grid_barrier(int* sync, int slot, int bid) {
    __syncthreads();
    if (threadIdx.x == 0) {
        __threadfence();
        int* gc  = sync + slot * 33 + (bid >> 6);
        int* rc  = sync + slot * 33 + 32;
        int* rel = sync + 99 + slot;
        if (__hip_atomic_fetch_add(gc, 1, __ATOMIC_ACQ_REL,
                                   __HIP_MEMORY_SCOPE_AGENT) == 63) {
            if (__hip_atomic_fetch_add(rc, 1, __ATOMIC_ACQ_REL,
                                       __HIP_MEMORY_SCOPE_AGENT) == 31) {
                __hip_atomic_store(rel, 1, __ATOMIC_RELEASE,
                                   __HIP_MEMORY_SCOPE_AGENT);
            }
        }
        while (__hip_atomic_load(rel, __ATOMIC_ACQUIRE,
                                 __HIP_MEMORY_SCOPE_AGENT) == 0)
            __builtin_amdgcn_s_sleep(2);
        __threadfence();
    }
    __syncthreads();
}

// ---- the fused persistent kernel ----
__global__ __launch_bounds__(128, 4) void k_fused(
        const float* x, const float* refl,
        const float* gw1, const float* gb1,
        const float* gw2, const float* gb2,
        const float* tap_w, const float* tap_b,
        const float* dw_w, const float* dw_b,
        const float* ln_g, const float* ln_b,
        const float* inp_w, const float* inp_b,
        const float* off_w, const float* off_b,
        const float* mask_w, const float* mask_b,
        const float* outp_w, const float* outp_b,
        const float* bn1_g, const float* bn1_b,
        const float* bn1_m, const float* bn1_v,
        const float* conv_w, const float* conv_b,
        const float* bn2_g, const float* bn2_b,
        const float* bn2_m, const float* bn2_v,
        float* pooled, float* gaing, float* xs, float* xpad,
        int* sync, float* out) {
    __shared__ float smem[2816];   // 11264 B: max over phases, aliased

    int tid  = threadIdx.x;
    int lane = tid & 63, wv = tid >> 6;
    int bid  = blockIdx.x;

    // ================= Phase 0: pool (blocks 0..511) =================
    if (bid < 512) {
        int nc = ((bid & 7) << 6) | (bid >> 3);     // n = b%8, c = b/8
        const float4* p4 = reinterpret_cast<const float4*>(x + (size_t)nc * 4096);
        float s = 0.f;
        for (int i = tid; i < 1024; i += 128) {
            float4 v = p4[i];
            s += v.x + v.y + v.z + v.w;
        }
        #pragma unroll
        for (int o = 32; o > 0; o >>= 1) s += __shfl_xor(s, o, 64);
        if (lane == 0) smem[wv] = s;
        __syncthreads();
        if (tid == 0) pooled[nc] = (smem[0] + smem[1]) * (1.f / 4096.f);
    }
    grid_barrier(sync, 0, bid);

    // ================= Phase 1: gain MLP (blocks 0..7, wave 0) =================
    if (bid < 8 && tid < 64) {
        int n = bid;
        float pv = pooled[n * 64 + lane];
        float part[16];
        const float4* g4 = reinterpret_cast<const float4*>(gw1 + lane * 16);
        #pragma unroll
        for (int q = 0; q < 4; ++q) {
            float4 v = g4[q];
            part[q * 4 + 0] = pv * v.x;
            part[q * 4 + 1] = pv * v.y;
            part[q * 4 + 2] = pv * v.z;
            part[q * 4 + 3] = pv * v.w;
        }
        #pragma unroll
        for (int o = 32; o > 0; o >>= 1) {
            #pragma unroll
            for (int j = 0; j < 16; ++j) part[j] += __shfl_xor(part[j], o, 64);
        }
        float acc = gb2[lane];
        #pragma unroll
        for (int j = 0; j < 16; ++j) {
            float hj = fmaxf(part[j] + gb1[j], 0.f);
            acc += hj * gw2[j * 64 + lane];
        }
        gaing[n * 64 + lane] = 1.f + 1.f / (1.f + __expf(-acc));
    }
    grid_barrier(sync, 1, bid);

    // ================= Phase 2: xs + input_proj + xpad (2 vblocks) =================
    {
        float (*xr)[64] = reinterpret_cast<float (*)[64]>(smem + wv * 256);
        for (int vb = bid; vb < 4096; vb += NBLK) {
            int n = vb & 7, rem = vb >> 3;          // XCD-locality swizzle
            int h = rem >> 3, wc = rem & 7;
            int w0 = wc * 8 + wv * 4;               // wave's first w
            int nh = n * 64 + h;

            {   // x (c=lane, 4 w's) -> regs; fuse gain + refl tap; write xs + strip
                float4 xv = *reinterpret_cast<const float4*>(
                    &x[(((size_t)(n * 64 + lane)) * 64 + h) * 64 + w0]);
                float gv = gaing[n * 64 + lane];
                float tw = tap_w[lane], tb = tap_b[lane];
                const float* rp = refl + n * 4096 + h * 64 + w0;
                float xvv[4] = {xv.x, xv.y, xv.z, xv.w};
                #pragma unroll
                for (int i = 0; i < 4; ++i) {
                    float r = fmaxf(rp[i] * tw + tb, 0.f);
                    float v = xvv[i] * gv + r;
                    xr[i][lane] = v;
                    xs[(((size_t)nh) * 64 + w0 + i) * 64 + lane] = v;
                }
            }
            WAVE_FENCE();

            {   // input_proj for 4 pixels; lane owns output channel co=lane.
                float acc[4];
                float bv = inp_b[lane];
                #pragma unroll
                for (int i = 0; i < 4; ++i) acc[i] = bv;
                #pragma unroll
                for (int c4 = 0; c4 < 64; c4 += 4) {
                    float q0 = inp_w[(c4 + 0) * 64 + lane];
                    float q1 = inp_w[(c4 + 1) * 64 + lane];
                    float q2 = inp_w[(c4 + 2) * 64 + lane];
                    float q3 = inp_w[(c4 + 3) * 64 + lane];
                    #pragma unroll
                    for (int i = 0; i < 4; ++i) {
                        float4 d = *reinterpret_cast<const float4*>(&xr[i][c4]);
                        acc[i] += d.x * q0 + d.y * q1 + d.z * q2 + d.w * q3;
                    }
                }
                const size_t rowb = (((size_t)n * 66) + (h + 1)) * 66;
                #pragma unroll
                for (int i = 0; i < 4; ++i)
                    xpad[(rowb + (w0 + i + 1)) * 64 + lane] = acc[i];
                if (w0 == 0)  xpad[rowb * 64 + lane] = 0.f;
                if (w0 == 60) xpad[(rowb + 65) * 64 + lane] = 0.f;
                if (h == 0 || h == 63) {
                    const size_t rb = (((size_t)n * 66) + (h == 0 ? 0 : 65)) * 66;
                    #pragma unroll
                    for (int i = 0; i < 4; ++i)
                        xpad[(rb + 1 + w0 + i) * 64 + lane] = 0.f;
                    if (w0 == 0)  xpad[rb * 64 + lane] = 0.f;
                    if (w0 == 60) xpad[(rb + 65) * 64 + lane] = 0.f;
                }
            }
            WAVE_FENCE();   // WAR: next vb's xr writes vs this vb's xr reads
        }
    }
    grid_barrier(sync, 2, bid);

    // ================= Phase 3: dwsamp (2 vblocks) =================
    {
        float*  chunk = smem + wv * 1408;
        int4*   sad   = reinterpret_cast<int4*>(chunk);           // [4][36]
        float*  dwr   = chunk;                                    // [4][64] aliases sad
        float4* swt   = reinterpret_cast<float4*>(chunk + 576);   // [4][36]
        float*  dcnl  = chunk + 1152;                             // [4][64]
        float*  mlog  = chunk + 1152;                             // [4][40] aliases dcnl

        for (int vb = bid; vb < 4096; vb += NBLK) {
            int n = vb & 7;                          // XCD-locality swizzle
            int pos0 = (vb >> 3) * 8 + wv * 4;       // wave's first pixel
            int h = pos0 >> 6, w0 = pos0 & 63;

            // ---- Phase A: depthwise 3x3 + LN + GELU, 4 pixels ----
            {
                float dwk[9];
                #pragma unroll
                for (int k = 0; k < 9; ++k) dwk[k] = dw_w[k * 64 + lane];
                float s[4];
                float bvv = dw_b[lane];
                #pragma unroll
                for (int p = 0; p < 4; ++p) s[p] = bvv;
                for (int ky = 0; ky < 3; ++ky) {
                    int y = h + ky - 1;
                    if (y < 0 || y > 63) continue;
                    const float* xrow = xs + ((size_t)(n * 64 + y)) * 4096;
                    float v[6];
                    #pragma unroll
                    for (int dx = 0; dx < 6; ++dx) {
                        int x2 = w0 - 1 + dx;
                        v[dx] = (x2 >= 0 && x2 <= 63) ? xrow[x2 * 64 + lane] : 0.f;
                    }
                    float k0 = dwk[ky * 3 + 0], k1 = dwk[ky * 3 + 1], k2 = dwk[ky * 3 + 2];
                    #pragma unroll
                    for (int p = 0; p < 4; ++p)
                        s[p] += v[p] * k0 + v[p + 1] * k1 + v[p + 2] * k2;
                }
                float lngv = ln_g[lane], lnbv = ln_b[lane];
                #pragma unroll
                for (int p = 0; p < 4; ++p) {
                    float sv = s[p];
                    float sum = sv, sq = sv * sv;
                    #pragma unroll
                    for (int o = 32; o > 0; o >>= 1) {
                        sum += __shfl_xor(sum, o, 64);
                        sq  += __shfl_xor(sq,  o, 64);
                    }
                    float mu = sum * (1.f / 64.f);
                    float var = sq * (1.f / 64.f) - mu * mu;
                    float nrm = (sv - mu) * rsqrtf(var + 1e-6f) * lngv + lnbv;
                    dwr[p * 64 + lane] = 0.5f * nrm * (1.f + erff(nrm * 0.70710678118654752f));
                }
            }
            WAVE_FENCE();

            // ---- Phase B: 108 projections x 4 pixels ----
            float a0[4], a1[4];
            {
                int jb = lane * 2;
                const float* wptr;
                int stride;
                float b0 = 0.f, b1 = 0.f;
                if (lane < 36)      { wptr = off_w + jb;         stride = 72; b0 = off_b[jb];       b1 = off_b[jb + 1]; }
                else if (lane < 54) { wptr = mask_w + (jb - 72); stride = 36; b0 = mask_b[jb - 72]; b1 = mask_b[jb - 71]; }
                else                { wptr = off_w;              stride = 0; }
                #pragma unroll
                for (int p = 0; p < 4; ++p) { a0[p] = b0; a1[p] = b1; }
                for (int c4 = 0; c4 < 64; c4 += 4) {
                    float4 d0 = *reinterpret_cast<const float4*>(&dwr[0 * 64 + c4]);
                    float4 d1 = *reinterpret_cast<const float4*>(&dwr[1 * 64 + c4]);
                    float4 d2 = *reinterpret_cast<const float4*>(&dwr[2 * 64 + c4]);
                    float4 d3 = *reinterpret_cast<const float4*>(&dwr[3 * 64 + c4]);
                    float dk0[4] = {d0.x, d0.y, d0.z, d0.w};
                    float dk1[4] = {d1.x, d1.y, d1.z, d1.w};
                    float dk2[4] = {d2.x, d2.y, d2.z, d2.w};
                    float dk3[4] = {d3.x, d3.y, d3.z, d3.w};
                    #pragma unroll
                    for (int k = 0; k < 4; ++k) {
                        float2 w2 = *reinterpret_cast<const float2*>(wptr);
                        wptr += stride;
                        a0[0] += dk0[k] * w2.x;  a1[0] += dk0[k] * w2.y;
                        a0[1] += dk1[k] * w2.x;  a1[1] += dk1[k] * w2.y;
                        a0[2] += dk2[k] * w2.x;  a1[2] += dk2[k] * w2.y;
                        a0[3] += dk3[k] * w2.x;  a1[3] += dk3[k] * w2.y;
                    }
                }
                if (lane >= 36 && lane < 54) {
                    int jm = lane * 2 - 72;
                    #pragma unroll
                    for (int p = 0; p < 4; ++p) {
                        mlog[p * 40 + jm]     = a0[p];
                        mlog[p * 40 + jm + 1] = a1[p];
                    }
                }
            }
            WAVE_FENCE();

            // ---- Phase B2 (lanes 0..35): softmax + coords/weights ----
            if (lane < 36) {
                int g = lane / 9, pp = lane - g * 9;
                #pragma unroll
                for (int p = 0; p < 4; ++p) {
                    const float* lrow = &mlog[p * 40 + g * 9];
                    float m = lrow[0];
                    #pragma unroll
                    for (int k = 1; k < 9; ++k) m = fmaxf(m, lrow[k]);
                    float ssum = 0.f, ek = 0.f;
                    #pragma unroll
                    for (int k = 0; k < 9; ++k) {
                        float e = __expf(lrow[k] - m);
                        ssum += e;
                        if (k == pp) ek = e;
                    }
                    float mk = ek / ssum;
                    float px = (float)((w0 + p) + (pp / 3)) + a0[p];
                    float py = (float)(h + (pp % 3)) + a1[p];
                    float x0f = floorf(px), y0f = floorf(py);
                    float wx = px - x0f, wy = py - y0f;
                    int x0 = (int)x0f, y0 = (int)y0f;
                    int x1 = x0 + 1, y1 = y0 + 1;
                    int xc0 = min(max(x0, 0), 65), xc1 = min(max(x1, 0), 65);
                    int yc0 = min(max(y0, 0), 65), yc1 = min(max(y1, 0), 65);
                    float vx0 = (x0 >= 0 && x0 < 66) ? 1.f : 0.f;
                    float vx1 = (x1 >= 0 && x1 < 66) ? 1.f : 0.f;
                    float vy0 = (y0 >= 0 && y0 < 66) ? 1.f : 0.f;
                    float vy1 = (y1 >= 0 && y1 < 66) ? 1.f : 0.f;
                    float wx0 = (1.f - wx) * vx0, wx1 = wx * vx1;
                    float wy0 = (1.f - wy) * vy0, wy1 = wy * vy1;
                    swt[p * 36 + lane] = make_float4(mk * wy0 * wx0, mk * wy0 * wx1,
                                                     mk * wy1 * wx0, mk * wy1 * wx1);
                    sad[p * 36 + lane] = make_int4((yc0 * 66 + xc0) * 64, (yc0 * 66 + xc1) * 64,
                                                   (yc1 * 66 + xc0) * 64, (yc1 * 66 + xc1) * 64);
                }
            }
            WAVE_FENCE();

            // ---- Phase C: bilinear sampling, load-all-then-reduce ----
            {
                int gb = (lane >> 4) * 9;
                const float* xpn = xpad + (size_t)n * 66 * 66 * 64;
                #pragma unroll
                for (int p = 0; p < 4; ++p) {
                    float t0[9], t1[9], t2[9], t3[9];
                    #pragma unroll
                    for (int pp = 0; pp < 9; ++pp) {
                        int4 a = sad[p * 36 + gb + pp];
                        t0[pp] = xpn[a.x + lane];
                        t1[pp] = xpn[a.y + lane];
                        t2[pp] = xpn[a.z + lane];
                        t3[pp] = xpn[a.w + lane];
                    }
                    float acc = 0.f;
                    #pragma unroll
                    for (int pp = 0; pp < 9; ++pp) {
                        float4 cw = swt[p * 36 + gb + pp];
                        acc += cw.x * t0[pp] + cw.y * t1[pp]
                             + cw.z * t2[pp] + cw.w * t3[pp];
                    }
                    dcnl[p * 64 + lane] = acc;
                }
            }
            WAVE_FENCE();

            // ---- Phase D: output_proj + BN1 + ReLU ----
            {
                float ob = outp_b[lane];
                float s0 = ob, s1 = ob, s2 = ob, s3 = ob;
                for (int c4 = 0; c4 < 64; c4 += 4) {
                    float w0v = outp_w[(c4 + 0) * 64 + lane];
                    float w1v = outp_w[(c4 + 1) * 64 + lane];
                    float w2v = outp_w[(c4 + 2) * 64 + lane];
                    float w3v = outp_w[(c4 + 3) * 64 + lane];
                    float4 d0 = *reinterpret_cast<const float4*>(&dcnl[0 * 64 + c4]);
                    float4 d1 = *reinterpret_cast<const float4*>(&dcnl[1 * 64 + c4]);
                    float4 d2 = *reinterpret_cast<const float4*>(&dcnl[2 * 64 + c4]);
                    float4 d3 = *reinterpret_cast<const float4*>(&dcnl[3 * 64 + c4]);
                    s0 += d0.x * w0v + d0.y * w1v + d0.z * w2v + d0.w * w3v;
                    s1 += d1.x * w0v + d1.y * w1v + d1.z * w2v + d1.w * w3v;
                    s2 += d2.x * w0v + d2.y * w1v + d2.z * w2v + d2.w * w3v;
                    s3 += d3.x * w0v + d3.y * w1v + d3.z * w2v + d3.w * w3v;
                }
                float sc = bn1_g[lane] * rsqrtf(bn1_v[lane] + 1e-5f);
                float sh = bn1_b[lane] - sc * bn1_m[lane];
                WAVE_FENCE();   // all reads of dcnl done before overwrite
                dcnl[0 * 64 + lane] = fmaxf(sc * s0 + sh, 0.f);
                dcnl[1 * 64 + lane] = fmaxf(sc * s1 + sh, 0.f);
                dcnl[2 * 64 + lane] = fmaxf(sc * s2 + sh, 0.f);
                dcnl[3 * 64 + lane] = fmaxf(sc * s3 + sh, 0.f);
            }
            WAVE_FENCE();

            // ---- Phase E: 1x1 conv 64->128 + BN2 + ReLU ----
            {
                float accA[4], accB[4];
                #pragma unroll
                for (int p = 0; p < 4; ++p) { accA[p] = 0.f; accB[p] = 0.f; }
                for (int c4 = 0; c4 < 64; c4 += 4) {
                    float4 d0 = *reinterpret_cast<const float4*>(&dcnl[0 * 64 + c4]);
                    float4 d1 = *reinterpret_cast<const float4*>(&dcnl[1 * 64 + c4]);
                    float4 d2 = *reinterpret_cast<const float4*>(&dcnl[2 * 64 + c4]);
                    float4 d3 = *reinterpret_cast<const float4*>(&dcnl[3 * 64 + c4]);
                    float dk0[4] = {d0.x, d0.y, d0.z, d0.w};
                    float dk1[4] = {d1.x, d1.y, d1.z, d1.w};
                    float dk2[4] = {d2.x, d2.y, d2.z, d2.w};
                    float dk3[4] = {d3.x, d3.y, d3.z, d3.w};
                    #pragma unroll
                    for (int k = 0; k < 4; ++k) {
                        float wa = conv_w[(c4 + k) * 128 + lane];
                        float wb = conv_w[(c4 + k) * 128 + 64 + lane];
                        accA[0] += dk0[k] * wa;  accB[0] += dk0[k] * wb;
                        accA[1] += dk1[k] * wa;  accB[1] += dk1[k] * wb;
                        accA[2] += dk2[k] * wa;  accB[2] += dk2[k] * wb;
                        accA[3] += dk3[k] * wa;  accB[3] += dk3[k] * wb;
                    }
                }
                int dA = lane, dB = lane + 64;
                float scA = bn2_g[dA] * rsqrtf(bn2_v[dA] + 1e-5f);
                float shA = scA * (conv_b[dA] - bn2_m[dA]) + bn2_b[dA];
                float scB = bn2_g[dB] * rsqrtf(bn2_v[dB] + 1e-5f);
                float shB = scB * (conv_b[dB] - bn2_m[dB]) + bn2_b[dB];
                float4 rA, rB;
                rA.x = fmaxf(scA * accA[0] + shA, 0.f);
                rA.y = fmaxf(scA * accA[1] + shA, 0.f);
                rA.z = fmaxf(scA * accA[2] + shA, 0.f);
                rA.w = fmaxf(scA * accA[3] + shA, 0.f);
                rB.x = fmaxf(scB * accB[0] + shB, 0.f);
                rB.y = fmaxf(scB * accB[1] + shB, 0.f);
                rB.z = fmaxf(scB * accB[2] + shB, 0.f);
                rB.w = fmaxf(scB * accB[3] + shB, 0.f);
                size_t oA = (((size_t)(n * 128 + dA)) * 64 + h) * 64 + w0;
                size_t oB = (((size_t)(n * 128 + dB)) * 64 + h) * 64 + w0;
                *reinterpret_cast<float4*>(out + oA) = rA;
                *reinterpret_cast<float4*>(out + oB) = rB;
            }
            WAVE_FENCE();   // WAR: next vb's LDS writes vs this vb's reads
        }
    }
}

extern "C" void kernel_launch(void* const* d_in, const int* in_sizes, int n_in,
                              void* d_out, int out_size, void* d_ws, size_t ws_size,
                              hipStream_t stream) {
    const float* x      = (const float*)d_in[0];
    const float* refl   = (const float*)d_in[1];
    const float* gw1    = (const float*)d_in[2];
    const float* gb1    = (const float*)d_in[3];
    const float* gw2    = (const float*)d_in[4];
    const float* gb2    = (const float*)d_in[5];
    const float* tap_w  = (const float*)d_in[6];
    const float* tap_b  = (const float*)d_in[7];
    const float* dw_w   = (const float*)d_in[8];
    const float* dw_b   = (const float*)d_in[9];
    const float* ln_g   = (const float*)d_in[10];
    const float* ln_b   = (const float*)d_in[11];
    const float* inp_w  = (const float*)d_in[12];
    const float* inp_b  = (const float*)d_in[13];
    const float* off_w  = (const float*)d_in[14];
    const float* off_b  = (const float*)d_in[15];
    const float* mask_w = (const float*)d_in[16];
    const float* mask_b = (const float*)d_in[17];
    const float* outp_w = (const float*)d_in[18];
    const float* outp_b = (const float*)d_in[19];
    const float* conv_w = (const float*)d_in[20];
    const float* conv_b = (const float*)d_in[21];
    const float* bn1_g  = (const float*)d_in[22];
    const float* bn1_b  = (const float*)d_in[23];
    const float* bn1_m  = (const float*)d_in[24];
    const float* bn1_v  = (const float*)d_in[25];
    const float* bn2_g  = (const float*)d_in[26];
    const float* bn2_b  = (const float*)d_in[27];
    const float* bn2_m  = (const float*)d_in[28];
    const float* bn2_v  = (const float*)d_in[29];

    // ws (floats): sync 128 | pooled 512 | gain 512 | xs 2,097,152 | xpad 2,230,272
    float* ws     = (float*)d_ws;
    int*   sync   = (int*)ws;              // 128 ints
    float* pooled = ws + 128;              // 512
    float* gaing  = ws + 640;              // 512
    float* xs     = ws + 1152;             // 2,097,152  (NHWC)
    float* xpad   = xs + 2097152;          // 2,230,272  (8*66*66*64, NHWC padded)

    k_init<<<1, 128, 0, stream>>>(sync);
    k_fused<<<NBLK, 128, 0, stream>>>(x, refl, gw1, gb1, gw2, gb2,
                                      tap_w, tap_b, dw_w, dw_b, ln_g, ln_b,
                                      inp_w, inp_b, off_w, off_b, mask_w, mask_b,
                                      outp_w, outp_b, bn1_g, bn1_b, bn1_m, bn1_v,
                                      conv_w, conv_b, bn2_g, bn2_b, bn2_m, bn2_v,
                                      pooled, gaing, xs, xpad, sync, (float*)d_out);
}

// Round 5
// 300.770 us; speedup vs baseline: 3.7725x; 3.7725x over previous
//
#include <hip/hip_runtime.h>
#include <math.h>

// Rod_Block: N=8, C_IN=64, C_OUT=128, G=4, CG=16, K=3, P=9, PAD=1, H=W=64.
// All tensors fp32. Padded spatial 66x66.
// Round-20: R4's persistent-kernel barrier was the disaster (ACQUIRE atomic
// poll = L2 invalidate per poll => 744 MB refetch, ~300us/barrier). Barrier
// v2: release-store arrival slots + block0 wave-scan with RELAXED loads +
// relaxed flag poll + ONE acquire fence per block per barrier.
// Structure: k_init | k_pre (2048 blocks: pool -> bar -> gain -> bar ->
// xsproj x2 vblocks, bodies verbatim R18/R19) | k_dwsamp (byte-identical
// R17 control, 4096x128).
// Co-residency of 2048 blocks @ launch_bounds(128,4): proven empirically in
// R4 (completed correctly).

#define NBLK_A 2048

// Wave-local LDS fence (unchanged from R16/R17).
#define WAVE_FENCE() asm volatile("s_waitcnt lgkmcnt(0)" ::: "memory")

// ---- init: zero sync area (2048 arrive slots + release flag; 2304 ints) ----
__global__ __launch_bounds__(256) void k_init(int* sync) {
    sync[blockIdx.x * 256 + threadIdx.x] = 0;
}

// Barrier v2. arrive[i]: generation counter per block; rel: generation flag.
// - Arrival: release-store (emits the L2 writeback that data publication
//   needs anyway). No RMW contention: one slot per block.
// - block 0, wave 0: scans all slots with RELAXED agent loads (no cache
//   maintenance), then release-stores rel = gen.
// - Waiters: RELAXED poll + s_sleep, then ONE acquire fence (single
//   invalidate per block per barrier, not per poll).
__device__ __forceinline__ void pbar(int* arrive, int* rel, int gen, int bid) {
    __syncthreads();
    if (threadIdx.x == 0)
        __hip_atomic_store(arrive + bid, gen, __ATOMIC_RELEASE,
                           __HIP_MEMORY_SCOPE_AGENT);
    if (bid == 0 && threadIdx.x < 64) {
        int lane = threadIdx.x;
        bool waiting = true;
        while (waiting) {
            bool ok = true;
            for (int i = lane; i < NBLK_A; i += 64) {
                if (__hip_atomic_load(arrive + i, __ATOMIC_RELAXED,
                                      __HIP_MEMORY_SCOPE_AGENT) < gen) {
                    ok = false;
                    break;
                }
            }
            if (__all(ok)) waiting = false;
            else __builtin_amdgcn_s_sleep(8);
        }
        if (lane == 0)
            __hip_atomic_store(rel, gen, __ATOMIC_RELEASE,
                               __HIP_MEMORY_SCOPE_AGENT);
    }
    if (threadIdx.x == 0) {
        while (__hip_atomic_load(rel, __ATOMIC_RELAXED,
                                 __HIP_MEMORY_SCOPE_AGENT) < gen)
            __builtin_amdgcn_s_sleep(16);
        __builtin_amdgcn_fence(__ATOMIC_ACQUIRE, "agent");
    }
    __syncthreads();
}

// ---- K_A: pool -> gain -> xs/input_proj/xpad, persistent, 2048 blocks ----
__global__ __launch_bounds__(128, 4) void k_pre(
        const float* x, const float* refl,
        const float* gw1, const float* gb1,
        const float* gw2, const float* gb2,
        const float* tap_w, const float* tap_b,
        const float* inp_w, const float* inp_b,
        float* pooled, float* gaing, float* xs, float* xpad, int* sync) {
    __shared__ float smem[512];   // phase0: 2 floats; phase2: xr 2x[4][64]
    int tid  = threadIdx.x;
    int lane = tid & 63, wv = tid >> 6;
    int bid  = blockIdx.x;
    int* arrive = sync;
    int* rel    = sync + 2048;

    // ---- Phase 0: pool (blocks 0..511); one (n,c) per block ----
    if (bid < 512) {
        int nc = ((bid & 7) << 6) | (bid >> 3);     // n = b%8, c = b/8
        const float4* p4 = reinterpret_cast<const float4*>(x + (size_t)nc * 4096);
        float s = 0.f;
        for (int i = tid; i < 1024; i += 128) {
            float4 v = p4[i];
            s += v.x + v.y + v.z + v.w;
        }
        #pragma unroll
        for (int o = 32; o > 0; o >>= 1) s += __shfl_xor(s, o, 64);
        if (lane == 0) smem[wv] = s;
        __syncthreads();
        if (tid == 0) pooled[nc] = (smem[0] + smem[1]) * (1.f / 4096.f);
    }
    pbar(arrive, rel, 1, bid);

    // ---- Phase 1: gain MLP (blocks 0..7, wave 0) ----
    if (bid < 8 && tid < 64) {
        int n = bid;
        float pv = pooled[n * 64 + lane];
        float part[16];
        const float4* g4 = reinterpret_cast<const float4*>(gw1 + lane * 16);
        #pragma unroll
        for (int q = 0; q < 4; ++q) {
            float4 v = g4[q];
            part[q * 4 + 0] = pv * v.x;
            part[q * 4 + 1] = pv * v.y;
            part[q * 4 + 2] = pv * v.z;
            part[q * 4 + 3] = pv * v.w;
        }
        #pragma unroll
        for (int o = 32; o > 0; o >>= 1) {
            #pragma unroll
            for (int j = 0; j < 16; ++j) part[j] += __shfl_xor(part[j], o, 64);
        }
        float acc = gb2[lane];
        #pragma unroll
        for (int j = 0; j < 16; ++j) {
            float hj = fmaxf(part[j] + gb1[j], 0.f);
            acc += hj * gw2[j * 64 + lane];
        }
        gaing[n * 64 + lane] = 1.f + 1.f / (1.f + __expf(-acc));
    }
    pbar(arrive, rel, 2, bid);

    // ---- Phase 2: xs + input_proj + xpad (2 vblocks per block) ----
    {
        float (*xr)[64] = reinterpret_cast<float (*)[64]>(smem + wv * 256);
        for (int vb = bid; vb < 4096; vb += NBLK_A) {
            int n = vb & 7, rem = vb >> 3;          // XCD-locality swizzle
            int h = rem >> 3, wc = rem & 7;
            int w0 = wc * 8 + wv * 4;               // wave's first w
            int nh = n * 64 + h;

            {   // x (c=lane, 4 w's) -> regs; fuse gain + refl tap; write xs + strip
                float4 xv = *reinterpret_cast<const float4*>(
                    &x[(((size_t)(n * 64 + lane)) * 64 + h) * 64 + w0]);
                float gv = gaing[n * 64 + lane];
                float tw = tap_w[lane], tb = tap_b[lane];
                const float* rp = refl + n * 4096 + h * 64 + w0;
                float xvv[4] = {xv.x, xv.y, xv.z, xv.w};
                #pragma unroll
                for (int i = 0; i < 4; ++i) {
                    float r = fmaxf(rp[i] * tw + tb, 0.f);
                    float v = xvv[i] * gv + r;
                    xr[i][lane] = v;
                    xs[(((size_t)nh) * 64 + w0 + i) * 64 + lane] = v;
                }
            }
            WAVE_FENCE();

            {   // input_proj for 4 pixels; lane owns output channel co=lane.
                float acc[4];
                float bv = inp_b[lane];
                #pragma unroll
                for (int i = 0; i < 4; ++i) acc[i] = bv;
                #pragma unroll
                for (int c4 = 0; c4 < 64; c4 += 4) {
                    float q0 = inp_w[(c4 + 0) * 64 + lane];
                    float q1 = inp_w[(c4 + 1) * 64 + lane];
                    float q2 = inp_w[(c4 + 2) * 64 + lane];
                    float q3 = inp_w[(c4 + 3) * 64 + lane];
                    #pragma unroll
                    for (int i = 0; i < 4; ++i) {
                        float4 d = *reinterpret_cast<const float4*>(&xr[i][c4]);
                        acc[i] += d.x * q0 + d.y * q1 + d.z * q2 + d.w * q3;
                    }
                }
                const size_t rowb = (((size_t)n * 66) + (h + 1)) * 66;
                #pragma unroll
                for (int i = 0; i < 4; ++i)
                    xpad[(rowb + (w0 + i + 1)) * 64 + lane] = acc[i];
                if (w0 == 0)  xpad[rowb * 64 + lane] = 0.f;
                if (w0 == 60) xpad[(rowb + 65) * 64 + lane] = 0.f;
                if (h == 0 || h == 63) {
                    const size_t rb = (((size_t)n * 66) + (h == 0 ? 0 : 65)) * 66;
                    #pragma unroll
                    for (int i = 0; i < 4; ++i)
                        xpad[(rb + 1 + w0 + i) * 64 + lane] = 0.f;
                    if (w0 == 0)  xpad[rb * 64 + lane] = 0.f;
                    if (w0 == 60) xpad[(rb + 65) * 64 + lane] = 0.f;
                }
            }
            WAVE_FENCE();   // WAR: next vb's xr writes vs this vb's xr reads
        }
    }
}

// ---- K_B: dwsamp, byte-identical R17 control ----
// 4096 blocks x 128 (2 fully independent waves); 4 px per wave.
__global__ __launch_bounds__(128, 4) void k_dwsamp(const float* xs, const float* xpad,
                       const float* dw_w, const float* dw_b,
                       const float* ln_g, const float* ln_b,
                       const float* off_w, const float* off_b,
                       const float* mask_w, const float* mask_b,
                       const float* outp_w, const float* outp_b,
                       const float* bn1_g, const float* bn1_b,
                       const float* bn1_m, const float* bn1_v,
                       const float* conv_w, const float* conv_b,
                       const float* bn2_g, const float* bn2_b,
                       const float* bn2_m, const float* bn2_v,
                       float* out) {
    __shared__ float smem[2816];

    int tid = threadIdx.x;
    int lane = tid & 63, wv = tid >> 6;      // wv in {0,1}
    float*  chunk = smem + wv * 1408;
    int4*   sad   = reinterpret_cast<int4*>(chunk);           // [4][36]
    float*  dwr   = chunk;                                    // [4][64] aliases sad
    float4* swt   = reinterpret_cast<float4*>(chunk + 576);   // [4][36]
    float*  dcnl  = chunk + 1152;                             // [4][64]
    float*  mlog  = chunk + 1152;                             // [4][40] aliases dcnl

    int b = blockIdx.x;
    int n = b & 7;                           // XCD-locality swizzle
    int pos0 = (b >> 3) * 8 + wv * 4;        // wave's first pixel within image
    int h = pos0 >> 6, w0 = pos0 & 63;       // 4 consecutive w on one row

    // ---- Phase A: depthwise 3x3 (6-column shared halo) + LN + GELU, 4 pixels ----
    {
        float dwk[9];
        #pragma unroll
        for (int k = 0; k < 9; ++k) dwk[k] = dw_w[k * 64 + lane];
        float s[4];
        float bvv = dw_b[lane];
        #pragma unroll
        for (int p = 0; p < 4; ++p) s[p] = bvv;
        for (int ky = 0; ky < 3; ++ky) {
            int y = h + ky - 1;
            if (y < 0 || y > 63) continue;
            const float* xrow = xs + ((size_t)(n * 64 + y)) * 4096;
            float v[6];
            #pragma unroll
            for (int dx = 0; dx < 6; ++dx) {
                int x2 = w0 - 1 + dx;
                v[dx] = (x2 >= 0 && x2 <= 63) ? xrow[x2 * 64 + lane] : 0.f;
            }
            float k0 = dwk[ky * 3 + 0], k1 = dwk[ky * 3 + 1], k2 = dwk[ky * 3 + 2];
            #pragma unroll
            for (int p = 0; p < 4; ++p)
                s[p] += v[p] * k0 + v[p + 1] * k1 + v[p + 2] * k2;
        }
        float lngv = ln_g[lane], lnbv = ln_b[lane];
        #pragma unroll
        for (int p = 0; p < 4; ++p) {
            float sv = s[p];
            float sum = sv, sq = sv * sv;
            #pragma unroll
            for (int o = 32; o > 0; o >>= 1) {
                sum += __shfl_xor(sum, o, 64);
                sq  += __shfl_xor(sq,  o, 64);
            }
            float mu = sum * (1.f / 64.f);
            float var = sq * (1.f / 64.f) - mu * mu;
            float nrm = (sv - mu) * rsqrtf(var + 1e-6f) * lngv + lnbv;
            dwr[p * 64 + lane] = 0.5f * nrm * (1.f + erff(nrm * 0.70710678118654752f));
        }
    }
    WAVE_FENCE();

    // ---- Phase B: 108 projections x 4 pixels; lane L<54 owns j={2L,2L+1}.
    float a0[4], a1[4];
    {
        int jb = lane * 2;
        const float* wptr;
        int stride;
        float b0 = 0.f, b1 = 0.f;
        if (lane < 36)      { wptr = off_w + jb;         stride = 72; b0 = off_b[jb];       b1 = off_b[jb + 1]; }
        else if (lane < 54) { wptr = mask_w + (jb - 72); stride = 36; b0 = mask_b[jb - 72]; b1 = mask_b[jb - 71]; }
        else                { wptr = off_w;              stride = 0; }
        #pragma unroll
        for (int p = 0; p < 4; ++p) { a0[p] = b0; a1[p] = b1; }
        for (int c4 = 0; c4 < 64; c4 += 4) {
            float4 d0 = *reinterpret_cast<const float4*>(&dwr[0 * 64 + c4]);
            float4 d1 = *reinterpret_cast<const float4*>(&dwr[1 * 64 + c4]);
            float4 d2 = *reinterpret_cast<const float4*>(&dwr[2 * 64 + c4]);
            float4 d3 = *reinterpret_cast<const float4*>(&dwr[3 * 64 + c4]);
            float dk0[4] = {d0.x, d0.y, d0.z, d0.w};
            float dk1[4] = {d1.x, d1.y, d1.z, d1.w};
            float dk2[4] = {d2.x, d2.y, d2.z, d2.w};
            float dk3[4] = {d3.x, d3.y, d3.z, d3.w};
            #pragma unroll
            for (int k = 0; k < 4; ++k) {
                float2 w2 = *reinterpret_cast<const float2*>(wptr);
                wptr += stride;
                a0[0] += dk0[k] * w2.x;  a1[0] += dk0[k] * w2.y;
                a0[1] += dk1[k] * w2.x;  a1[1] += dk1[k] * w2.y;
                a0[2] += dk2[k] * w2.x;  a1[2] += dk2[k] * w2.y;
                a0[3] += dk3[k] * w2.x;  a1[3] += dk3[k] * w2.y;
            }
        }
        if (lane >= 36 && lane < 54) {
            int jm = lane * 2 - 72;           // 0..34 even
            #pragma unroll
            for (int p = 0; p < 4; ++p) {
                mlog[p * 40 + jm]     = a0[p];
                mlog[p * 40 + jm + 1] = a1[p];
            }
        }
    }
    WAVE_FENCE();

    // ---- Phase B2 (lanes 0..35): softmax + sampling coords/weights per pixel ----
    if (lane < 36) {
        int g = lane / 9, pp = lane - g * 9;
        #pragma unroll
        for (int p = 0; p < 4; ++p) {
            const float* lrow = &mlog[p * 40 + g * 9];
            float m = lrow[0];
            #pragma unroll
            for (int k = 1; k < 9; ++k) m = fmaxf(m, lrow[k]);
            float ssum = 0.f, ek = 0.f;
            #pragma unroll
            for (int k = 0; k < 9; ++k) {
                float e = __expf(lrow[k] - m);
                ssum += e;
                if (k == pp) ek = e;
            }
            float mk = ek / ssum;
            float px = (float)((w0 + p) + (pp / 3)) + a0[p];   // kernel grid w-outer/h-inner
            float py = (float)(h + (pp % 3)) + a1[p];
            float x0f = floorf(px), y0f = floorf(py);
            float wx = px - x0f, wy = py - y0f;
            int x0 = (int)x0f, y0 = (int)y0f;
            int x1 = x0 + 1, y1 = y0 + 1;
            int xc0 = min(max(x0, 0), 65), xc1 = min(max(x1, 0), 65);
            int yc0 = min(max(y0, 0), 65), yc1 = min(max(y1, 0), 65);
            float vx0 = (x0 >= 0 && x0 < 66) ? 1.f : 0.f;
            float vx1 = (x1 >= 0 && x1 < 66) ? 1.f : 0.f;
            float vy0 = (y0 >= 0 && y0 < 66) ? 1.f : 0.f;
            float vy1 = (y1 >= 0 && y1 < 66) ? 1.f : 0.f;
            float wx0 = (1.f - wx) * vx0, wx1 = wx * vx1;
            float wy0 = (1.f - wy) * vy0, wy1 = wy * vy1;
            swt[p * 36 + lane] = make_float4(mk * wy0 * wx0, mk * wy0 * wx1,
                                             mk * wy1 * wx0, mk * wy1 * wx1);
            sad[p * 36 + lane] = make_int4((yc0 * 66 + xc0) * 64, (yc0 * 66 + xc1) * 64,
                                           (yc1 * 66 + xc0) * 64, (yc1 * 66 + xc1) * 64);
        }
    }
    WAVE_FENCE();

    // ---- Phase C: bilinear deformable sampling, 4 pixels ----
    // Load-all-then-reduce: all 36 gather loads of a pixel are issued into
    // register arrays before any FMA consumes them (deep VMEM pipelining).
    {
        int gb = (lane >> 4) * 9;
        const float* xpn = xpad + (size_t)n * 66 * 66 * 64;
        #pragma unroll
        for (int p = 0; p < 4; ++p) {
            float t0[9], t1[9], t2[9], t3[9];
            #pragma unroll
            for (int pp = 0; pp < 9; ++pp) {
                int4 a = sad[p * 36 + gb + pp];
                t0[pp] = xpn[a.x + lane];
                t1[pp] = xpn[a.y + lane];
                t2[pp] = xpn[a.z + lane];
                t3[pp] = xpn[a.w + lane];
            }
            float acc = 0.f;
            #pragma unroll
            for (int pp = 0; pp < 9; ++pp) {
                float4 cw = swt[p * 36 + gb + pp];
                acc += cw.x * t0[pp] + cw.y * t1[pp]
                     + cw.z * t2[pp] + cw.w * t3[pp];
            }
            dcnl[p * 64 + lane] = acc;
        }
    }
    WAVE_FENCE();

    // ---- Phase D: output_proj + BN1 + ReLU -> overwrite dcnl with vbuf values ----
    {
        float ob = outp_b[lane];
        float s0 = ob, s1 = ob, s2 = ob, s3 = ob;
        for (int c4 = 0; c4 < 64; c4 += 4) {
            float w0v = outp_w[(c4 + 0) * 64 + lane];
            float w1v = outp_w[(c4 + 1) * 64 + lane];
            float w2v = outp_w[(c4 + 2) * 64 + lane];
            float w3v = outp_w[(c4 + 3) * 64 + lane];
            float4 d0 = *reinterpret_cast<const float4*>(&dcnl[0 * 64 + c4]);
            float4 d1 = *reinterpret_cast<const float4*>(&dcnl[1 * 64 + c4]);
            float4 d2 = *reinterpret_cast<const float4*>(&dcnl[2 * 64 + c4]);
            float4 d3 = *reinterpret_cast<const float4*>(&dcnl[3 * 64 + c4]);
            s0 += d0.x * w0v + d0.y * w1v + d0.z * w2v + d0.w * w3v;
            s1 += d1.x * w0v + d1.y * w1v + d1.z * w2v + d1.w * w3v;
            s2 += d2.x * w0v + d2.y * w1v + d2.z * w2v + d2.w * w3v;
            s3 += d3.x * w0v + d3.y * w1v + d3.z * w2v + d3.w * w3v;
        }
        float sc = bn1_g[lane] * rsqrtf(bn1_v[lane] + 1e-5f);
        float sh = bn1_b[lane] - sc * bn1_m[lane];
        WAVE_FENCE();   // all reads of dcnl done before overwrite below
        dcnl[0 * 64 + lane] = fmaxf(sc * s0 + sh, 0.f);
        dcnl[1 * 64 + lane] = fmaxf(sc * s1 + sh, 0.f);
        dcnl[2 * 64 + lane] = fmaxf(sc * s2 + sh, 0.f);
        dcnl[3 * 64 + lane] = fmaxf(sc * s3 + sh, 0.f);
    }
    WAVE_FENCE();

    // ---- Phase E: 1x1 conv 64->128 + BN2 + ReLU; lane = d and d+64; float4 store along w ----
    {
        float accA[4], accB[4];   // [px] for d=lane, d=lane+64
        #pragma unroll
        for (int p = 0; p < 4; ++p) { accA[p] = 0.f; accB[p] = 0.f; }
        for (int c4 = 0; c4 < 64; c4 += 4) {
            float4 d0 = *reinterpret_cast<const float4*>(&dcnl[0 * 64 + c4]);
            float4 d1 = *reinterpret_cast<const float4*>(&dcnl[1 * 64 + c4]);
            float4 d2 = *reinterpret_cast<const float4*>(&dcnl[2 * 64 + c4]);
            float4 d3 = *reinterpret_cast<const float4*>(&dcnl[3 * 64 + c4]);
            float dk0[4] = {d0.x, d0.y, d0.z, d0.w};
            float dk1[4] = {d1.x, d1.y, d1.z, d1.w};
            float dk2[4] = {d2.x, d2.y, d2.z, d2.w};
            float dk3[4] = {d3.x, d3.y, d3.z, d3.w};
            #pragma unroll
            for (int k = 0; k < 4; ++k) {
                float wa = conv_w[(c4 + k) * 128 + lane];
                float wb = conv_w[(c4 + k) * 128 + 64 + lane];
                accA[0] += dk0[k] * wa;  accB[0] += dk0[k] * wb;
                accA[1] += dk1[k] * wa;  accB[1] += dk1[k] * wb;
                accA[2] += dk2[k] * wa;  accB[2] += dk2[k] * wb;
                accA[3] += dk3[k] * wa;  accB[3] += dk3[k] * wb;
            }
        }
        int dA = lane, dB = lane + 64;
        float scA = bn2_g[dA] * rsqrtf(bn2_v[dA] + 1e-5f);
        float shA = scA * (conv_b[dA] - bn2_m[dA]) + bn2_b[dA];
        float scB = bn2_g[dB] * rsqrtf(bn2_v[dB] + 1e-5f);
        float shB = scB * (conv_b[dB] - bn2_m[dB]) + bn2_b[dB];
        float4 rA, rB;
        rA.x = fmaxf(scA * accA[0] + shA, 0.f);
        rA.y = fmaxf(scA * accA[1] + shA, 0.f);
        rA.z = fmaxf(scA * accA[2] + shA, 0.f);
        rA.w = fmaxf(scA * accA[3] + shA, 0.f);
        rB.x = fmaxf(scB * accB[0] + shB, 0.f);
        rB.y = fmaxf(scB * accB[1] + shB, 0.f);
        rB.z = fmaxf(scB * accB[2] + shB, 0.f);
        rB.w = fmaxf(scB * accB[3] + shB, 0.f);
        size_t oA = (((size_t)(n * 128 + dA)) * 64 + h) * 64 + w0;
        size_t oB = (((size_t)(n * 128 + dB)) * 64 + h) * 64 + w0;
        *reinterpret_cast<float4*>(out + oA) = rA;
        *reinterpret_cast<float4*>(out + oB) = rB;
    }
}

extern "C" void kernel_launch(void* const* d_in, const int* in_sizes, int n_in,
                              void* d_out, int out_size, void* d_ws, size_t ws_size,
                              hipStream_t stream) {
    const float* x      = (const float*)d_in[0];
    const float* refl   = (const float*)d_in[1];
    const float* gw1    = (const float*)d_in[2];
    const float* gb1    = (const float*)d_in[3];
    const float* gw2    = (const float*)d_in[4];
    const float* gb2    = (const float*)d_in[5];
    const float* tap_w  = (const float*)d_in[6];
    const float* tap_b  = (const float*)d_in[7];
    const float* dw_w   = (const float*)d_in[8];
    const float* dw_b   = (const float*)d_in[9];
    const float* ln_g   = (const float*)d_in[10];
    const float* ln_b   = (const float*)d_in[11];
    const float* inp_w  = (const float*)d_in[12];
    const float* inp_b  = (const float*)d_in[13];
    const float* off_w  = (const float*)d_in[14];
    const float* off_b  = (const float*)d_in[15];
    const float* mask_w = (const float*)d_in[16];
    const float* mask_b = (const float*)d_in[17];
    const float* outp_w = (const float*)d_in[18];
    const float* outp_b = (const float*)d_in[19];
    const float* conv_w = (const float*)d_in[20];
    const float* conv_b = (const float*)d_in[21];
    const float* bn1_g  = (const float*)d_in[22];
    const float* bn1_b  = (const float*)d_in[23];
    const float* bn1_m  = (const float*)d_in[24];
    const float* bn1_v  = (const float*)d_in[25];
    const float* bn2_g  = (const float*)d_in[26];
    const float* bn2_b  = (const float*)d_in[27];
    const float* bn2_m  = (const float*)d_in[28];
    const float* bn2_v  = (const float*)d_in[29];

    // ws (floats): sync 2304 | pooled 512 | gain 512 | xs 2,097,152 | xpad 2,230,272
    float* ws     = (float*)d_ws;
    int*   sync   = (int*)ws;              // 2304 ints (2048 arrive + rel + pad)
    float* pooled = ws + 2304;             // 512
    float* gaing  = ws + 2816;             // 512
    float* xs     = ws + 3328;             // 2,097,152  (NHWC)
    float* xpad   = xs + 2097152;          // 2,230,272  (8*66*66*64, NHWC padded)

    k_init<<<9, 256, 0, stream>>>(sync);
    k_pre<<<NBLK_A, 128, 0, stream>>>(x, refl, gw1, gb1, gw2, gb2,
                                      tap_w, tap_b, inp_w, inp_b,
                                      pooled, gaing, xs, xpad, sync);
    k_dwsamp<<<4096, 128, 0, stream>>>(xs, xpad, dw_w, dw_b, ln_g, ln_b,
                                       off_w, off_b, mask_w, mask_b,
                                       outp_w, outp_b, bn1_g, bn1_b, bn1_m, bn1_v,
                                       conv_w, conv_b, bn2_g, bn2_b, bn2_m, bn2_v,
                                       (float*)d_out);
}

// Round 6
// 197.890 us; speedup vs baseline: 5.7337x; 1.5199x over previous
//
#include <hip/hip_runtime.h>
#include <math.h>

// Rod_Block: N=8, C_IN=64, C_OUT=128, G=4, CG=16, K=3, P=9, PAD=1, H=W=64.
// All tensors fp32. Padded spatial 66x66.
// Round-21: persistent-fusion path abandoned (R4/R5: grid barriers cost
// 30-300us each). Back to the 4-dispatch R2/R3 pipeline. Single change:
// k_xsproj v5 — 512 blocks x 256, block=(n,h) covers a FULL 64-wide row so
// the x tile load is 256B-coalesced per channel row (the old versions read
// 64 separate 16KB-strided planes per wave => L2-latency bound).
// k_pool / k_gain / k_dwsamp byte-identical (controls).

// Wave-local LDS fence (R16/R17).
#define WAVE_FENCE() asm volatile("s_waitcnt lgkmcnt(0)" ::: "memory")

// ---- K1: pooled[n,c] = mean_{h,w} x[n,c,h,w]  (512 blocks x 256) ----
__global__ __launch_bounds__(256) void k_pool(const float* x, float* pooled) {
    __shared__ float red[256];
    int b = blockIdx.x;
    int nc = ((b & 7) << 6) | (b >> 3);     // n = b%8, c = b/8
    const float4* p4 = reinterpret_cast<const float4*>(x + (size_t)nc * 4096);
    float s = 0.f;
    for (int i = threadIdx.x; i < 1024; i += 256) {
        float4 v = p4[i];
        s += v.x + v.y + v.z + v.w;
    }
    red[threadIdx.x] = s;
    __syncthreads();
    for (int o = 128; o > 0; o >>= 1) {
        if (threadIdx.x < o) red[threadIdx.x] += red[threadIdx.x + o];
        __syncthreads();
    }
    if (threadIdx.x == 0) pooled[nc] = red[0] * (1.f / 4096.f);
}

// ---- K1b: gain[n,c] = 1 + sigmoid(MLP(pooled[n,:]))  (8 blocks x 64) ----
__global__ __launch_bounds__(64) void k_gain(const float* pooled,
        const float* gw1, const float* gb1,
        const float* gw2, const float* gb2,
        float* gain) {
    int n = blockIdx.x;
    int lane = threadIdx.x;
    float pv = pooled[n * 64 + lane];
    float part[16];
    const float4* g4 = reinterpret_cast<const float4*>(gw1 + lane * 16);
    #pragma unroll
    for (int q = 0; q < 4; ++q) {
        float4 v = g4[q];
        part[q * 4 + 0] = pv * v.x;
        part[q * 4 + 1] = pv * v.y;
        part[q * 4 + 2] = pv * v.z;
        part[q * 4 + 3] = pv * v.w;
    }
    #pragma unroll
    for (int o = 32; o > 0; o >>= 1) {
        #pragma unroll
        for (int j = 0; j < 16; ++j) part[j] += __shfl_xor(part[j], o, 64);
    }
    float acc = gb2[lane];
    #pragma unroll
    for (int j = 0; j < 16; ++j) {
        float hj = fmaxf(part[j] + gb1[j], 0.f);
        acc += hj * gw2[j * 64 + lane];
    }
    gain[n * 64 + lane] = 1.f + 1.f / (1.f + __expf(-acc));
}

// ---- K2 v5: xs(NHWC) + input_proj + xpad, full-row blocks ----
// 512 blocks x 256 threads; block = (n = b&7, h = b>>3).
// LDS: tile[c][w] (x row-tile, coalesced load), xsw[w][c] (xs, w-major,
// 68-stride => 16B-aligned float4 rows), rr (refl row).
__global__ __launch_bounds__(256) void k_xsproj(
        const float* x, const float* refl,
        const float* tap_w, const float* tap_b,
        const float* gain,
        const float* inp_w, const float* inp_b,
        float* xs, float* xpad) {
    __shared__ float tile[64][65];
    __shared__ float xsw[64][68];
    __shared__ float rr[64];
    int t = threadIdx.x;
    int b = blockIdx.x;
    int n = b & 7, h = b >> 3;              // XCD-locality swizzle
    int c = t & 63, g = t >> 6;             // phase2/3 mapping

    // phase 1: stage x[n,:,h,:] (64 rows x 64 w) -- 256B-coalesced per row
    #pragma unroll
    for (int it = 0; it < 4; ++it) {
        int f = it * 256 + t;               // float4 index in tile
        int cc = f >> 4, w4 = (f & 15) * 4;
        float4 v = *reinterpret_cast<const float4*>(
            &x[(((size_t)(n * 64 + cc)) * 64 + h) * 64 + w4]);
        tile[cc][w4 + 0] = v.x;
        tile[cc][w4 + 1] = v.y;
        tile[cc][w4 + 2] = v.z;
        tile[cc][w4 + 3] = v.w;
    }
    if (t < 64) rr[t] = refl[n * 4096 + h * 64 + t];
    __syncthreads();

    // phase 2: xs = x*gain + relu(refl*tapw+tapb); thread = (c, 16 w's)
    {
        float gv = gain[n * 64 + c];
        float tw = tap_w[c], tb = tap_b[c];
        float* xsg = xs + (((size_t)(n * 64 + h)) * 64) * 64 + c;
        #pragma unroll
        for (int k = 0; k < 16; ++k) {
            int w = g * 16 + k;
            float r = fmaxf(rr[w] * tw + tb, 0.f);
            float v = tile[c][w] * gv + r;
            xsw[w][c] = v;
            xsg[(size_t)w * 64] = v;
        }
    }
    __syncthreads();

    // phase 3: input_proj; thread = (co = c, 16 w's); xsw reads broadcast
    {
        float acc[16];
        float bv = inp_b[c];
        #pragma unroll
        for (int k = 0; k < 16; ++k) acc[k] = bv;
        for (int c4 = 0; c4 < 64; c4 += 4) {
            float q0 = inp_w[(c4 + 0) * 64 + c];
            float q1 = inp_w[(c4 + 1) * 64 + c];
            float q2 = inp_w[(c4 + 2) * 64 + c];
            float q3 = inp_w[(c4 + 3) * 64 + c];
            #pragma unroll
            for (int k = 0; k < 16; ++k) {
                float4 d = *reinterpret_cast<const float4*>(&xsw[g * 16 + k][c4]);
                acc[k] += d.x * q0 + d.y * q1 + d.z * q2 + d.w * q3;
            }
        }
        const size_t rowb = (((size_t)n * 66) + (h + 1)) * 66;
        #pragma unroll
        for (int k = 0; k < 16; ++k) {
            int w = g * 16 + k;
            xpad[(rowb + (w + 1)) * 64 + c] = acc[k];
        }
        if (g == 0) xpad[rowb * 64 + c] = 0.f;
        if (g == 3) xpad[(rowb + 65) * 64 + c] = 0.f;
        if (h == 0 || h == 63) {
            const size_t base = ((((size_t)n * 66) + (h == 0 ? 0 : 65)) * 66) * 64;
            for (int i = t; i < 66 * 64; i += 256) xpad[base + i] = 0.f;
        }
    }
}

// ---- K3: dwsamp (byte-identical R17 control) ----
// 4096 blocks x 128 (2 fully independent waves); 4 px per wave.
__global__ __launch_bounds__(128, 4) void k_dwsamp(const float* xs, const float* xpad,
                       const float* dw_w, const float* dw_b,
                       const float* ln_g, const float* ln_b,
                       const float* off_w, const float* off_b,
                       const float* mask_w, const float* mask_b,
                       const float* outp_w, const float* outp_b,
                       const float* bn1_g, const float* bn1_b,
                       const float* bn1_m, const float* bn1_v,
                       const float* conv_w, const float* conv_b,
                       const float* bn2_g, const float* bn2_b,
                       const float* bn2_m, const float* bn2_v,
                       float* out) {
    __shared__ float smem[2816];

    int tid = threadIdx.x;
    int lane = tid & 63, wv = tid >> 6;      // wv in {0,1}
    float*  chunk = smem + wv * 1408;
    int4*   sad   = reinterpret_cast<int4*>(chunk);           // [4][36]
    float*  dwr   = chunk;                                    // [4][64] aliases sad
    float4* swt   = reinterpret_cast<float4*>(chunk + 576);   // [4][36]
    float*  dcnl  = chunk + 1152;                             // [4][64]
    float*  mlog  = chunk + 1152;                             // [4][40] aliases dcnl

    int b = blockIdx.x;
    int n = b & 7;                           // XCD-locality swizzle
    int pos0 = (b >> 3) * 8 + wv * 4;        // wave's first pixel within image
    int h = pos0 >> 6, w0 = pos0 & 63;       // 4 consecutive w on one row

    // ---- Phase A: depthwise 3x3 (6-column shared halo) + LN + GELU, 4 pixels ----
    {
        float dwk[9];
        #pragma unroll
        for (int k = 0; k < 9; ++k) dwk[k] = dw_w[k * 64 + lane];
        float s[4];
        float bvv = dw_b[lane];
        #pragma unroll
        for (int p = 0; p < 4; ++p) s[p] = bvv;
        for (int ky = 0; ky < 3; ++ky) {
            int y = h + ky - 1;
            if (y < 0 || y > 63) continue;
            const float* xrow = xs + ((size_t)(n * 64 + y)) * 4096;
            float v[6];
            #pragma unroll
            for (int dx = 0; dx < 6; ++dx) {
                int x2 = w0 - 1 + dx;
                v[dx] = (x2 >= 0 && x2 <= 63) ? xrow[x2 * 64 + lane] : 0.f;
            }
            float k0 = dwk[ky * 3 + 0], k1 = dwk[ky * 3 + 1], k2 = dwk[ky * 3 + 2];
            #pragma unroll
            for (int p = 0; p < 4; ++p)
                s[p] += v[p] * k0 + v[p + 1] * k1 + v[p + 2] * k2;
        }
        float lngv = ln_g[lane], lnbv = ln_b[lane];
        #pragma unroll
        for (int p = 0; p < 4; ++p) {
            float sv = s[p];
            float sum = sv, sq = sv * sv;
            #pragma unroll
            for (int o = 32; o > 0; o >>= 1) {
                sum += __shfl_xor(sum, o, 64);
                sq  += __shfl_xor(sq,  o, 64);
            }
            float mu = sum * (1.f / 64.f);
            float var = sq * (1.f / 64.f) - mu * mu;
            float nrm = (sv - mu) * rsqrtf(var + 1e-6f) * lngv + lnbv;
            dwr[p * 64 + lane] = 0.5f * nrm * (1.f + erff(nrm * 0.70710678118654752f));
        }
    }
    WAVE_FENCE();

    // ---- Phase B: 108 projections x 4 pixels; lane L<54 owns j={2L,2L+1}.
    float a0[4], a1[4];
    {
        int jb = lane * 2;
        const float* wptr;
        int stride;
        float b0 = 0.f, b1 = 0.f;
        if (lane < 36)      { wptr = off_w + jb;         stride = 72; b0 = off_b[jb];       b1 = off_b[jb + 1]; }
        else if (lane < 54) { wptr = mask_w + (jb - 72); stride = 36; b0 = mask_b[jb - 72]; b1 = mask_b[jb - 71]; }
        else                { wptr = off_w;              stride = 0; }
        #pragma unroll
        for (int p = 0; p < 4; ++p) { a0[p] = b0; a1[p] = b1; }
        for (int c4 = 0; c4 < 64; c4 += 4) {
            float4 d0 = *reinterpret_cast<const float4*>(&dwr[0 * 64 + c4]);
            float4 d1 = *reinterpret_cast<const float4*>(&dwr[1 * 64 + c4]);
            float4 d2 = *reinterpret_cast<const float4*>(&dwr[2 * 64 + c4]);
            float4 d3 = *reinterpret_cast<const float4*>(&dwr[3 * 64 + c4]);
            float dk0[4] = {d0.x, d0.y, d0.z, d0.w};
            float dk1[4] = {d1.x, d1.y, d1.z, d1.w};
            float dk2[4] = {d2.x, d2.y, d2.z, d2.w};
            float dk3[4] = {d3.x, d3.y, d3.z, d3.w};
            #pragma unroll
            for (int k = 0; k < 4; ++k) {
                float2 w2 = *reinterpret_cast<const float2*>(wptr);
                wptr += stride;
                a0[0] += dk0[k] * w2.x;  a1[0] += dk0[k] * w2.y;
                a0[1] += dk1[k] * w2.x;  a1[1] += dk1[k] * w2.y;
                a0[2] += dk2[k] * w2.x;  a1[2] += dk2[k] * w2.y;
                a0[3] += dk3[k] * w2.x;  a1[3] += dk3[k] * w2.y;
            }
        }
        if (lane >= 36 && lane < 54) {
            int jm = lane * 2 - 72;           // 0..34 even
            #pragma unroll
            for (int p = 0; p < 4; ++p) {
                mlog[p * 40 + jm]     = a0[p];
                mlog[p * 40 + jm + 1] = a1[p];
            }
        }
    }
    WAVE_FENCE();

    // ---- Phase B2 (lanes 0..35): softmax + sampling coords/weights per pixel ----
    if (lane < 36) {
        int g = lane / 9, pp = lane - g * 9;
        #pragma unroll
        for (int p = 0; p < 4; ++p) {
            const float* lrow = &mlog[p * 40 + g * 9];
            float m = lrow[0];
            #pragma unroll
            for (int k = 1; k < 9; ++k) m = fmaxf(m, lrow[k]);
            float ssum = 0.f, ek = 0.f;
            #pragma unroll
            for (int k = 0; k < 9; ++k) {
                float e = __expf(lrow[k] - m);
                ssum += e;
                if (k == pp) ek = e;
            }
            float mk = ek / ssum;
            float px = (float)((w0 + p) + (pp / 3)) + a0[p];   // kernel grid w-outer/h-inner
            float py = (float)(h + (pp % 3)) + a1[p];
            float x0f = floorf(px), y0f = floorf(py);
            float wx = px - x0f, wy = py - y0f;
            int x0 = (int)x0f, y0 = (int)y0f;
            int x1 = x0 + 1, y1 = y0 + 1;
            int xc0 = min(max(x0, 0), 65), xc1 = min(max(x1, 0), 65);
            int yc0 = min(max(y0, 0), 65), yc1 = min(max(y1, 0), 65);
            float vx0 = (x0 >= 0 && x0 < 66) ? 1.f : 0.f;
            float vx1 = (x1 >= 0 && x1 < 66) ? 1.f : 0.f;
            float vy0 = (y0 >= 0 && y0 < 66) ? 1.f : 0.f;
            float vy1 = (y1 >= 0 && y1 < 66) ? 1.f : 0.f;
            float wx0 = (1.f - wx) * vx0, wx1 = wx * vx1;
            float wy0 = (1.f - wy) * vy0, wy1 = wy * vy1;
            swt[p * 36 + lane] = make_float4(mk * wy0 * wx0, mk * wy0 * wx1,
                                             mk * wy1 * wx0, mk * wy1 * wx1);
            sad[p * 36 + lane] = make_int4((yc0 * 66 + xc0) * 64, (yc0 * 66 + xc1) * 64,
                                           (yc1 * 66 + xc0) * 64, (yc1 * 66 + xc1) * 64);
        }
    }
    WAVE_FENCE();

    // ---- Phase C: bilinear deformable sampling, 4 pixels ----
    // Load-all-then-reduce: all 36 gather loads of a pixel are issued into
    // register arrays before any FMA consumes them (deep VMEM pipelining).
    {
        int gb = (lane >> 4) * 9;
        const float* xpn = xpad + (size_t)n * 66 * 66 * 64;
        #pragma unroll
        for (int p = 0; p < 4; ++p) {
            float t0[9], t1[9], t2[9], t3[9];
            #pragma unroll
            for (int pp = 0; pp < 9; ++pp) {
                int4 a = sad[p * 36 + gb + pp];
                t0[pp] = xpn[a.x + lane];
                t1[pp] = xpn[a.y + lane];
                t2[pp] = xpn[a.z + lane];
                t3[pp] = xpn[a.w + lane];
            }
            float acc = 0.f;
            #pragma unroll
            for (int pp = 0; pp < 9; ++pp) {
                float4 cw = swt[p * 36 + gb + pp];
                acc += cw.x * t0[pp] + cw.y * t1[pp]
                     + cw.z * t2[pp] + cw.w * t3[pp];
            }
            dcnl[p * 64 + lane] = acc;
        }
    }
    WAVE_FENCE();

    // ---- Phase D: output_proj + BN1 + ReLU -> overwrite dcnl with vbuf values ----
    {
        float ob = outp_b[lane];
        float s0 = ob, s1 = ob, s2 = ob, s3 = ob;
        for (int c4 = 0; c4 < 64; c4 += 4) {
            float w0v = outp_w[(c4 + 0) * 64 + lane];
            float w1v = outp_w[(c4 + 1) * 64 + lane];
            float w2v = outp_w[(c4 + 2) * 64 + lane];
            float w3v = outp_w[(c4 + 3) * 64 + lane];
            float4 d0 = *reinterpret_cast<const float4*>(&dcnl[0 * 64 + c4]);
            float4 d1 = *reinterpret_cast<const float4*>(&dcnl[1 * 64 + c4]);
            float4 d2 = *reinterpret_cast<const float4*>(&dcnl[2 * 64 + c4]);
            float4 d3 = *reinterpret_cast<const float4*>(&dcnl[3 * 64 + c4]);
            s0 += d0.x * w0v + d0.y * w1v + d0.z * w2v + d0.w * w3v;
            s1 += d1.x * w0v + d1.y * w1v + d1.z * w2v + d1.w * w3v;
            s2 += d2.x * w0v + d2.y * w1v + d2.z * w2v + d2.w * w3v;
            s3 += d3.x * w0v + d3.y * w1v + d3.z * w2v + d3.w * w3v;
        }
        float sc = bn1_g[lane] * rsqrtf(bn1_v[lane] + 1e-5f);
        float sh = bn1_b[lane] - sc * bn1_m[lane];
        WAVE_FENCE();   // all reads of dcnl done before overwrite below
        dcnl[0 * 64 + lane] = fmaxf(sc * s0 + sh, 0.f);
        dcnl[1 * 64 + lane] = fmaxf(sc * s1 + sh, 0.f);
        dcnl[2 * 64 + lane] = fmaxf(sc * s2 + sh, 0.f);
        dcnl[3 * 64 + lane] = fmaxf(sc * s3 + sh, 0.f);
    }
    WAVE_FENCE();

    // ---- Phase E: 1x1 conv 64->128 + BN2 + ReLU; lane = d and d+64; float4 store along w ----
    {
        float accA[4], accB[4];   // [px] for d=lane, d=lane+64
        #pragma unroll
        for (int p = 0; p < 4; ++p) { accA[p] = 0.f; accB[p] = 0.f; }
        for (int c4 = 0; c4 < 64; c4 += 4) {
            float4 d0 = *reinterpret_cast<const float4*>(&dcnl[0 * 64 + c4]);
            float4 d1 = *reinterpret_cast<const float4*>(&dcnl[1 * 64 + c4]);
            float4 d2 = *reinterpret_cast<const float4*>(&dcnl[2 * 64 + c4]);
            float4 d3 = *reinterpret_cast<const float4*>(&dcnl[3 * 64 + c4]);
            float dk0[4] = {d0.x, d0.y, d0.z, d0.w};
            float dk1[4] = {d1.x, d1.y, d1.z, d1.w};
            float dk2[4] = {d2.x, d2.y, d2.z, d2.w};
            float dk3[4] = {d3.x, d3.y, d3.z, d3.w};
            #pragma unroll
            for (int k = 0; k < 4; ++k) {
                float wa = conv_w[(c4 + k) * 128 + lane];
                float wb = conv_w[(c4 + k) * 128 + 64 + lane];
                accA[0] += dk0[k] * wa;  accB[0] += dk0[k] * wb;
                accA[1] += dk1[k] * wa;  accB[1] += dk1[k] * wb;
                accA[2] += dk2[k] * wa;  accB[2] += dk2[k] * wb;
                accA[3] += dk3[k] * wa;  accB[3] += dk3[k] * wb;
            }
        }
        int dA = lane, dB = lane + 64;
        float scA = bn2_g[dA] * rsqrtf(bn2_v[dA] + 1e-5f);
        float shA = scA * (conv_b[dA] - bn2_m[dA]) + bn2_b[dA];
        float scB = bn2_g[dB] * rsqrtf(bn2_v[dB] + 1e-5f);
        float shB = scB * (conv_b[dB] - bn2_m[dB]) + bn2_b[dB];
        float4 rA, rB;
        rA.x = fmaxf(scA * accA[0] + shA, 0.f);
        rA.y = fmaxf(scA * accA[1] + shA, 0.f);
        rA.z = fmaxf(scA * accA[2] + shA, 0.f);
        rA.w = fmaxf(scA * accA[3] + shA, 0.f);
        rB.x = fmaxf(scB * accB[0] + shB, 0.f);
        rB.y = fmaxf(scB * accB[1] + shB, 0.f);
        rB.z = fmaxf(scB * accB[2] + shB, 0.f);
        rB.w = fmaxf(scB * accB[3] + shB, 0.f);
        size_t oA = (((size_t)(n * 128 + dA)) * 64 + h) * 64 + w0;
        size_t oB = (((size_t)(n * 128 + dB)) * 64 + h) * 64 + w0;
        *reinterpret_cast<float4*>(out + oA) = rA;
        *reinterpret_cast<float4*>(out + oB) = rB;
    }
}

extern "C" void kernel_launch(void* const* d_in, const int* in_sizes, int n_in,
                              void* d_out, int out_size, void* d_ws, size_t ws_size,
                              hipStream_t stream) {
    const float* x      = (const float*)d_in[0];
    const float* refl   = (const float*)d_in[1];
    const float* gw1    = (const float*)d_in[2];
    const float* gb1    = (const float*)d_in[3];
    const float* gw2    = (const float*)d_in[4];
    const float* gb2    = (const float*)d_in[5];
    const float* tap_w  = (const float*)d_in[6];
    const float* tap_b  = (const float*)d_in[7];
    const float* dw_w   = (const float*)d_in[8];
    const float* dw_b   = (const float*)d_in[9];
    const float* ln_g   = (const float*)d_in[10];
    const float* ln_b   = (const float*)d_in[11];
    const float* inp_w  = (const float*)d_in[12];
    const float* inp_b  = (const float*)d_in[13];
    const float* off_w  = (const float*)d_in[14];
    const float* off_b  = (const float*)d_in[15];
    const float* mask_w = (const float*)d_in[16];
    const float* mask_b = (const float*)d_in[17];
    const float* outp_w = (const float*)d_in[18];
    const float* outp_b = (const float*)d_in[19];
    const float* conv_w = (const float*)d_in[20];
    const float* conv_b = (const float*)d_in[21];
    const float* bn1_g  = (const float*)d_in[22];
    const float* bn1_b  = (const float*)d_in[23];
    const float* bn1_m  = (const float*)d_in[24];
    const float* bn1_v  = (const float*)d_in[25];
    const float* bn2_g  = (const float*)d_in[26];
    const float* bn2_b  = (const float*)d_in[27];
    const float* bn2_m  = (const float*)d_in[28];
    const float* bn2_v  = (const float*)d_in[29];

    // ws (floats): pooled 512 | gain 512 | xs 2,097,152 | xpad 2,230,272
    float* ws     = (float*)d_ws;
    float* pooled = ws;                    // 512
    float* gaing  = ws + 512;              // 512
    float* xs     = ws + 1024;             // 2,097,152  (NHWC)
    float* xpad   = xs + 2097152;          // 2,230,272  (8*66*66*64, NHWC padded)

    k_pool<<<512, 256, 0, stream>>>(x, pooled);
    k_gain<<<8, 64, 0, stream>>>(pooled, gw1, gb1, gw2, gb2, gaing);
    k_xsproj<<<512, 256, 0, stream>>>(x, refl, tap_w, tap_b, gaing,
                                      inp_w, inp_b, xs, xpad);
    k_dwsamp<<<4096, 128, 0, stream>>>(xs, xpad, dw_w, dw_b, ln_g, ln_b,
                                       off_w, off_b, mask_w, mask_b,
                                       outp_w, outp_b, bn1_g, bn1_b, bn1_m, bn1_v,
                                       conv_w, conv_b, bn2_g, bn2_b, bn2_m, bn2_v,
                                       (float*)d_out);
}

// Round 7
// 190.485 us; speedup vs baseline: 5.9566x; 1.0389x over previous
//
#include <hip/hip_runtime.h>
#include <math.h>

// Rod_Block: N=8, C_IN=64, C_OUT=128, G=4, CG=16, K=3, P=9, PAD=1, H=W=64.
// All tensors fp32. Padded spatial 66x66.
// Round-22: (1) 3 dispatches — gain-MLP folded into k_xsproj (wave 1
// recomputes the 2KFLOP MLP per block, ~0.25us, hidden under staging);
// (2) k_dwsamp phases B/D/E accumulators restructured as float2 pairs with
// an explicit fused-pair helper to invite v_pk_fma_f32 (VOP3P packed fp32,
// 2 FMAs/issue). Numerics bitwise-identical (per-output chains unchanged).
// k_pool byte-identical control.

// Wave-local LDS fence (R16/R17).
#define WAVE_FENCE() asm volatile("s_waitcnt lgkmcnt(0)" ::: "memory")

// Packed-pair FMA: acc.{x,y} += s * v.{x,y}. The float2-typed accumulator
// and operand keep the pair in adjacent VGPRs -> LLVM can fold the two
// v_fmac into one v_pk_fma_f32 (broadcast s via op_sel).
__device__ __forceinline__ float2 fma2s(float s, float2 v, float2 acc) {
    acc.x = fmaf(s, v.x, acc.x);
    acc.y = fmaf(s, v.y, acc.y);
    return acc;
}

// ---- K1: pooled[n,c] = mean_{h,w} x[n,c,h,w]  (512 blocks x 256) ----
__global__ __launch_bounds__(256) void k_pool(const float* x, float* pooled) {
    __shared__ float red[256];
    int b = blockIdx.x;
    int nc = ((b & 7) << 6) | (b >> 3);     // n = b%8, c = b/8
    const float4* p4 = reinterpret_cast<const float4*>(x + (size_t)nc * 4096);
    float s = 0.f;
    for (int i = threadIdx.x; i < 1024; i += 256) {
        float4 v = p4[i];
        s += v.x + v.y + v.z + v.w;
    }
    red[threadIdx.x] = s;
    __syncthreads();
    for (int o = 128; o > 0; o >>= 1) {
        if (threadIdx.x < o) red[threadIdx.x] += red[threadIdx.x + o];
        __syncthreads();
    }
    if (threadIdx.x == 0) pooled[nc] = red[0] * (1.f / 4096.f);
}

// ---- K2 v6: gain-MLP (in-block) + xs(NHWC) + input_proj + xpad ----
// 512 blocks x 256 threads; block = (n = b&7, h = b>>3).
__global__ __launch_bounds__(256) void k_xsproj(
        const float* x, const float* refl,
        const float* tap_w, const float* tap_b,
        const float* pooled,
        const float* gw1, const float* gb1,
        const float* gw2, const float* gb2,
        const float* inp_w, const float* inp_b,
        float* xs, float* xpad) {
    __shared__ float tile[64][65];
    __shared__ float xsw[64][68];
    __shared__ float rr[64];
    __shared__ float gbuf[64];
    int t = threadIdx.x;
    int b = blockIdx.x;
    int n = b & 7, h = b >> 3;              // XCD-locality swizzle
    int c = t & 63, g = t >> 6;             // phase2/3 mapping

    // phase 1: stage x[n,:,h,:] (64 rows x 64 w) -- 256B-coalesced per row
    #pragma unroll
    for (int it = 0; it < 4; ++it) {
        int f = it * 256 + t;               // float4 index in tile
        int cc = f >> 4, w4 = (f & 15) * 4;
        float4 v = *reinterpret_cast<const float4*>(
            &x[(((size_t)(n * 64 + cc)) * 64 + h) * 64 + w4]);
        tile[cc][w4 + 0] = v.x;
        tile[cc][w4 + 1] = v.y;
        tile[cc][w4 + 2] = v.z;
        tile[cc][w4 + 3] = v.w;
    }
    if (t < 64) rr[t] = refl[n * 4096 + h * 64 + t];
    // wave 1: gain[n][lane] = 1 + sigmoid(MLP(pooled[n,:])) -- ~0.25us
    if (t >= 64 && t < 128) {
        int lane = t - 64;
        float pv = pooled[n * 64 + lane];
        float part[16];
        const float4* g4 = reinterpret_cast<const float4*>(gw1 + lane * 16);
        #pragma unroll
        for (int q = 0; q < 4; ++q) {
            float4 v = g4[q];
            part[q * 4 + 0] = pv * v.x;
            part[q * 4 + 1] = pv * v.y;
            part[q * 4 + 2] = pv * v.z;
            part[q * 4 + 3] = pv * v.w;
        }
        #pragma unroll
        for (int o = 32; o > 0; o >>= 1) {
            #pragma unroll
            for (int j = 0; j < 16; ++j) part[j] += __shfl_xor(part[j], o, 64);
        }
        float acc = gb2[lane];
        #pragma unroll
        for (int j = 0; j < 16; ++j) {
            float hj = fmaxf(part[j] + gb1[j], 0.f);
            acc += hj * gw2[j * 64 + lane];
        }
        gbuf[lane] = 1.f + 1.f / (1.f + __expf(-acc));
    }
    __syncthreads();

    // phase 2: xs = x*gain + relu(refl*tapw+tapb); thread = (c, 16 w's)
    {
        float gv = gbuf[c];
        float tw = tap_w[c], tb = tap_b[c];
        float* xsg = xs + (((size_t)(n * 64 + h)) * 64) * 64 + c;
        #pragma unroll
        for (int k = 0; k < 16; ++k) {
            int w = g * 16 + k;
            float r = fmaxf(rr[w] * tw + tb, 0.f);
            float v = tile[c][w] * gv + r;
            xsw[w][c] = v;
            xsg[(size_t)w * 64] = v;
        }
    }
    __syncthreads();

    // phase 3: input_proj; thread = (co = c, 16 w's); xsw reads broadcast
    {
        float acc[16];
        float bv = inp_b[c];
        #pragma unroll
        for (int k = 0; k < 16; ++k) acc[k] = bv;
        for (int c4 = 0; c4 < 64; c4 += 4) {
            float q0 = inp_w[(c4 + 0) * 64 + c];
            float q1 = inp_w[(c4 + 1) * 64 + c];
            float q2 = inp_w[(c4 + 2) * 64 + c];
            float q3 = inp_w[(c4 + 3) * 64 + c];
            #pragma unroll
            for (int k = 0; k < 16; ++k) {
                float4 d = *reinterpret_cast<const float4*>(&xsw[g * 16 + k][c4]);
                acc[k] += d.x * q0 + d.y * q1 + d.z * q2 + d.w * q3;
            }
        }
        const size_t rowb = (((size_t)n * 66) + (h + 1)) * 66;
        #pragma unroll
        for (int k = 0; k < 16; ++k) {
            int w = g * 16 + k;
            xpad[(rowb + (w + 1)) * 64 + c] = acc[k];
        }
        if (g == 0) xpad[rowb * 64 + c] = 0.f;
        if (g == 3) xpad[(rowb + 65) * 64 + c] = 0.f;
        if (h == 0 || h == 63) {
            const size_t base = ((((size_t)n * 66) + (h == 0 ? 0 : 65)) * 66) * 64;
            for (int i = t; i < 66 * 64; i += 256) xpad[base + i] = 0.f;
        }
    }
}

// ---- K3: dwsamp v4 — R17 structure + float2-paired GEMM accumulators ----
// 4096 blocks x 128 (2 fully independent waves); 4 px per wave.
__global__ __launch_bounds__(128, 4) void k_dwsamp(const float* xs, const float* xpad,
                       const float* dw_w, const float* dw_b,
                       const float* ln_g, const float* ln_b,
                       const float* off_w, const float* off_b,
                       const float* mask_w, const float* mask_b,
                       const float* outp_w, const float* outp_b,
                       const float* bn1_g, const float* bn1_b,
                       const float* bn1_m, const float* bn1_v,
                       const float* conv_w, const float* conv_b,
                       const float* bn2_g, const float* bn2_b,
                       const float* bn2_m, const float* bn2_v,
                       float* out) {
    __shared__ float smem[2816];

    int tid = threadIdx.x;
    int lane = tid & 63, wv = tid >> 6;      // wv in {0,1}
    float*  chunk = smem + wv * 1408;
    int4*   sad   = reinterpret_cast<int4*>(chunk);           // [4][36]
    float*  dwr   = chunk;                                    // [4][64] aliases sad
    float4* swt   = reinterpret_cast<float4*>(chunk + 576);   // [4][36]
    float*  dcnl  = chunk + 1152;                             // [4][64]
    float*  mlog  = chunk + 1152;                             // [4][40] aliases dcnl

    int b = blockIdx.x;
    int n = b & 7;                           // XCD-locality swizzle
    int pos0 = (b >> 3) * 8 + wv * 4;        // wave's first pixel within image
    int h = pos0 >> 6, w0 = pos0 & 63;       // 4 consecutive w on one row

    // ---- Phase A: depthwise 3x3 (6-column shared halo) + LN + GELU, 4 pixels ----
    {
        float dwk[9];
        #pragma unroll
        for (int k = 0; k < 9; ++k) dwk[k] = dw_w[k * 64 + lane];
        float s[4];
        float bvv = dw_b[lane];
        #pragma unroll
        for (int p = 0; p < 4; ++p) s[p] = bvv;
        for (int ky = 0; ky < 3; ++ky) {
            int y = h + ky - 1;
            if (y < 0 || y > 63) continue;
            const float* xrow = xs + ((size_t)(n * 64 + y)) * 4096;
            float v[6];
            #pragma unroll
            for (int dx = 0; dx < 6; ++dx) {
                int x2 = w0 - 1 + dx;
                v[dx] = (x2 >= 0 && x2 <= 63) ? xrow[x2 * 64 + lane] : 0.f;
            }
            float k0 = dwk[ky * 3 + 0], k1 = dwk[ky * 3 + 1], k2 = dwk[ky * 3 + 2];
            #pragma unroll
            for (int p = 0; p < 4; ++p)
                s[p] += v[p] * k0 + v[p + 1] * k1 + v[p + 2] * k2;
        }
        float lngv = ln_g[lane], lnbv = ln_b[lane];
        #pragma unroll
        for (int p = 0; p < 4; ++p) {
            float sv = s[p];
            float sum = sv, sq = sv * sv;
            #pragma unroll
            for (int o = 32; o > 0; o >>= 1) {
                sum += __shfl_xor(sum, o, 64);
                sq  += __shfl_xor(sq,  o, 64);
            }
            float mu = sum * (1.f / 64.f);
            float var = sq * (1.f / 64.f) - mu * mu;
            float nrm = (sv - mu) * rsqrtf(var + 1e-6f) * lngv + lnbv;
            dwr[p * 64 + lane] = 0.5f * nrm * (1.f + erff(nrm * 0.70710678118654752f));
        }
    }
    WAVE_FENCE();

    // ---- Phase B: 108 projections x 4 pixels; lane L<54 owns j={2L,2L+1}.
    // Accumulators as float2 pairs (j, j+1) -> v_pk_fma_f32 candidate.
    float2 a01[4];
    {
        int jb = lane * 2;
        const float* wptr;
        int stride;
        float b0 = 0.f, b1 = 0.f;
        if (lane < 36)      { wptr = off_w + jb;         stride = 72; b0 = off_b[jb];       b1 = off_b[jb + 1]; }
        else if (lane < 54) { wptr = mask_w + (jb - 72); stride = 36; b0 = mask_b[jb - 72]; b1 = mask_b[jb - 71]; }
        else                { wptr = off_w;              stride = 0; }
        #pragma unroll
        for (int p = 0; p < 4; ++p) a01[p] = make_float2(b0, b1);
        for (int c4 = 0; c4 < 64; c4 += 4) {
            float4 d0 = *reinterpret_cast<const float4*>(&dwr[0 * 64 + c4]);
            float4 d1 = *reinterpret_cast<const float4*>(&dwr[1 * 64 + c4]);
            float4 d2 = *reinterpret_cast<const float4*>(&dwr[2 * 64 + c4]);
            float4 d3 = *reinterpret_cast<const float4*>(&dwr[3 * 64 + c4]);
            float dk0[4] = {d0.x, d0.y, d0.z, d0.w};
            float dk1[4] = {d1.x, d1.y, d1.z, d1.w};
            float dk2[4] = {d2.x, d2.y, d2.z, d2.w};
            float dk3[4] = {d3.x, d3.y, d3.z, d3.w};
            #pragma unroll
            for (int k = 0; k < 4; ++k) {
                float2 w2 = *reinterpret_cast<const float2*>(wptr);
                wptr += stride;
                a01[0] = fma2s(dk0[k], w2, a01[0]);
                a01[1] = fma2s(dk1[k], w2, a01[1]);
                a01[2] = fma2s(dk2[k], w2, a01[2]);
                a01[3] = fma2s(dk3[k], w2, a01[3]);
            }
        }
        if (lane >= 36 && lane < 54) {
            int jm = lane * 2 - 72;           // 0..34 even
            #pragma unroll
            for (int p = 0; p < 4; ++p) {
                mlog[p * 40 + jm]     = a01[p].x;
                mlog[p * 40 + jm + 1] = a01[p].y;
            }
        }
    }
    WAVE_FENCE();

    // ---- Phase B2 (lanes 0..35): softmax + sampling coords/weights per pixel ----
    if (lane < 36) {
        int g = lane / 9, pp = lane - g * 9;
        #pragma unroll
        for (int p = 0; p < 4; ++p) {
            const float* lrow = &mlog[p * 40 + g * 9];
            float m = lrow[0];
            #pragma unroll
            for (int k = 1; k < 9; ++k) m = fmaxf(m, lrow[k]);
            float ssum = 0.f, ek = 0.f;
            #pragma unroll
            for (int k = 0; k < 9; ++k) {
                float e = __expf(lrow[k] - m);
                ssum += e;
                if (k == pp) ek = e;
            }
            float mk = ek / ssum;
            float px = (float)((w0 + p) + (pp / 3)) + a01[p].x;   // kernel grid w-outer/h-inner
            float py = (float)(h + (pp % 3)) + a01[p].y;
            float x0f = floorf(px), y0f = floorf(py);
            float wx = px - x0f, wy = py - y0f;
            int x0 = (int)x0f, y0 = (int)y0f;
            int x1 = x0 + 1, y1 = y0 + 1;
            int xc0 = min(max(x0, 0), 65), xc1 = min(max(x1, 0), 65);
            int yc0 = min(max(y0, 0), 65), yc1 = min(max(y1, 0), 65);
            float vx0 = (x0 >= 0 && x0 < 66) ? 1.f : 0.f;
            float vx1 = (x1 >= 0 && x1 < 66) ? 1.f : 0.f;
            float vy0 = (y0 >= 0 && y0 < 66) ? 1.f : 0.f;
            float vy1 = (y1 >= 0 && y1 < 66) ? 1.f : 0.f;
            float wx0 = (1.f - wx) * vx0, wx1 = wx * vx1;
            float wy0 = (1.f - wy) * vy0, wy1 = wy * vy1;
            swt[p * 36 + lane] = make_float4(mk * wy0 * wx0, mk * wy0 * wx1,
                                             mk * wy1 * wx0, mk * wy1 * wx1);
            sad[p * 36 + lane] = make_int4((yc0 * 66 + xc0) * 64, (yc0 * 66 + xc1) * 64,
                                           (yc1 * 66 + xc0) * 64, (yc1 * 66 + xc1) * 64);
        }
    }
    WAVE_FENCE();

    // ---- Phase C: bilinear deformable sampling, 4 pixels ----
    // Load-all-then-reduce: all 36 gather loads of a pixel are issued into
    // register arrays before any FMA consumes them (deep VMEM pipelining).
    {
        int gb = (lane >> 4) * 9;
        const float* xpn = xpad + (size_t)n * 66 * 66 * 64;
        #pragma unroll
        for (int p = 0; p < 4; ++p) {
            float t0[9], t1[9], t2[9], t3[9];
            #pragma unroll
            for (int pp = 0; pp < 9; ++pp) {
                int4 a = sad[p * 36 + gb + pp];
                t0[pp] = xpn[a.x + lane];
                t1[pp] = xpn[a.y + lane];
                t2[pp] = xpn[a.z + lane];
                t3[pp] = xpn[a.w + lane];
            }
            float acc = 0.f;
            #pragma unroll
            for (int pp = 0; pp < 9; ++pp) {
                float4 cw = swt[p * 36 + gb + pp];
                acc += cw.x * t0[pp] + cw.y * t1[pp]
                     + cw.z * t2[pp] + cw.w * t3[pp];
            }
            dcnl[p * 64 + lane] = acc;
        }
    }
    WAVE_FENCE();

    // ---- Phase D: output_proj + BN1 + ReLU; pixel-paired float2 accums ----
    {
        float ob = outp_b[lane];
        float2 s01 = make_float2(ob, ob), s23 = make_float2(ob, ob);
        for (int c4 = 0; c4 < 64; c4 += 4) {
            float w0v = outp_w[(c4 + 0) * 64 + lane];
            float w1v = outp_w[(c4 + 1) * 64 + lane];
            float w2v = outp_w[(c4 + 2) * 64 + lane];
            float w3v = outp_w[(c4 + 3) * 64 + lane];
            float4 d0 = *reinterpret_cast<const float4*>(&dcnl[0 * 64 + c4]);
            float4 d1 = *reinterpret_cast<const float4*>(&dcnl[1 * 64 + c4]);
            float4 d2 = *reinterpret_cast<const float4*>(&dcnl[2 * 64 + c4]);
            float4 d3 = *reinterpret_cast<const float4*>(&dcnl[3 * 64 + c4]);
            s01 = fma2s(w0v, make_float2(d0.x, d1.x), s01);
            s01 = fma2s(w1v, make_float2(d0.y, d1.y), s01);
            s01 = fma2s(w2v, make_float2(d0.z, d1.z), s01);
            s01 = fma2s(w3v, make_float2(d0.w, d1.w), s01);
            s23 = fma2s(w0v, make_float2(d2.x, d3.x), s23);
            s23 = fma2s(w1v, make_float2(d2.y, d3.y), s23);
            s23 = fma2s(w2v, make_float2(d2.z, d3.z), s23);
            s23 = fma2s(w3v, make_float2(d2.w, d3.w), s23);
        }
        float sc = bn1_g[lane] * rsqrtf(bn1_v[lane] + 1e-5f);
        float sh = bn1_b[lane] - sc * bn1_m[lane];
        WAVE_FENCE();   // all reads of dcnl done before overwrite below
        dcnl[0 * 64 + lane] = fmaxf(sc * s01.x + sh, 0.f);
        dcnl[1 * 64 + lane] = fmaxf(sc * s01.y + sh, 0.f);
        dcnl[2 * 64 + lane] = fmaxf(sc * s23.x + sh, 0.f);
        dcnl[3 * 64 + lane] = fmaxf(sc * s23.y + sh, 0.f);
    }
    WAVE_FENCE();

    // ---- Phase E: 1x1 conv 64->128 + BN2 + ReLU; channel-paired float2 ----
    {
        float2 acc2[4];   // [px]: .x -> d=lane, .y -> d=lane+64
        #pragma unroll
        for (int p = 0; p < 4; ++p) acc2[p] = make_float2(0.f, 0.f);
        for (int c4 = 0; c4 < 64; c4 += 4) {
            float4 d0 = *reinterpret_cast<const float4*>(&dcnl[0 * 64 + c4]);
            float4 d1 = *reinterpret_cast<const float4*>(&dcnl[1 * 64 + c4]);
            float4 d2 = *reinterpret_cast<const float4*>(&dcnl[2 * 64 + c4]);
            float4 d3 = *reinterpret_cast<const float4*>(&dcnl[3 * 64 + c4]);
            float dk0[4] = {d0.x, d0.y, d0.z, d0.w};
            float dk1[4] = {d1.x, d1.y, d1.z, d1.w};
            float dk2[4] = {d2.x, d2.y, d2.z, d2.w};
            float dk3[4] = {d3.x, d3.y, d3.z, d3.w};
            #pragma unroll
            for (int k = 0; k < 4; ++k) {
                float2 w2 = make_float2(conv_w[(c4 + k) * 128 + lane],
                                        conv_w[(c4 + k) * 128 + 64 + lane]);
                acc2[0] = fma2s(dk0[k], w2, acc2[0]);
                acc2[1] = fma2s(dk1[k], w2, acc2[1]);
                acc2[2] = fma2s(dk2[k], w2, acc2[2]);
                acc2[3] = fma2s(dk3[k], w2, acc2[3]);
            }
        }
        int dA = lane, dB = lane + 64;
        float scA = bn2_g[dA] * rsqrtf(bn2_v[dA] + 1e-5f);
        float shA = scA * (conv_b[dA] - bn2_m[dA]) + bn2_b[dA];
        float scB = bn2_g[dB] * rsqrtf(bn2_v[dB] + 1e-5f);
        float shB = scB * (conv_b[dB] - bn2_m[dB]) + bn2_b[dB];
        float4 rA, rB;
        rA.x = fmaxf(scA * acc2[0].x + shA, 0.f);
        rA.y = fmaxf(scA * acc2[1].x + shA, 0.f);
        rA.z = fmaxf(scA * acc2[2].x + shA, 0.f);
        rA.w = fmaxf(scA * acc2[3].x + shA, 0.f);
        rB.x = fmaxf(scB * acc2[0].y + shB, 0.f);
        rB.y = fmaxf(scB * acc2[1].y + shB, 0.f);
        rB.z = fmaxf(scB * acc2[2].y + shB, 0.f);
        rB.w = fmaxf(scB * acc2[3].y + shB, 0.f);
        size_t oA = (((size_t)(n * 128 + dA)) * 64 + h) * 64 + w0;
        size_t oB = (((size_t)(n * 128 + dB)) * 64 + h) * 64 + w0;
        *reinterpret_cast<float4*>(out + oA) = rA;
        *reinterpret_cast<float4*>(out + oB) = rB;
    }
}

extern "C" void kernel_launch(void* const* d_in, const int* in_sizes, int n_in,
                              void* d_out, int out_size, void* d_ws, size_t ws_size,
                              hipStream_t stream) {
    const float* x      = (const float*)d_in[0];
    const float* refl   = (const float*)d_in[1];
    const float* gw1    = (const float*)d_in[2];
    const float* gb1    = (const float*)d_in[3];
    const float* gw2    = (const float*)d_in[4];
    const float* gb2    = (const float*)d_in[5];
    const float* tap_w  = (const float*)d_in[6];
    const float* tap_b  = (const float*)d_in[7];
    const float* dw_w   = (const float*)d_in[8];
    const float* dw_b   = (const float*)d_in[9];
    const float* ln_g   = (const float*)d_in[10];
    const float* ln_b   = (const float*)d_in[11];
    const float* inp_w  = (const float*)d_in[12];
    const float* inp_b  = (const float*)d_in[13];
    const float* off_w  = (const float*)d_in[14];
    const float* off_b  = (const float*)d_in[15];
    const float* mask_w = (const float*)d_in[16];
    const float* mask_b = (const float*)d_in[17];
    const float* outp_w = (const float*)d_in[18];
    const float* outp_b = (const float*)d_in[19];
    const float* conv_w = (const float*)d_in[20];
    const float* conv_b = (const float*)d_in[21];
    const float* bn1_g  = (const float*)d_in[22];
    const float* bn1_b  = (const float*)d_in[23];
    const float* bn1_m  = (const float*)d_in[24];
    const float* bn1_v  = (const float*)d_in[25];
    const float* bn2_g  = (const float*)d_in[26];
    const float* bn2_b  = (const float*)d_in[27];
    const float* bn2_m  = (const float*)d_in[28];
    const float* bn2_v  = (const float*)d_in[29];

    // ws (floats): pooled 512 | xs 2,097,152 | xpad 2,230,272
    float* ws     = (float*)d_ws;
    float* pooled = ws;                    // 512
    float* xs     = ws + 512;              // 2,097,152  (NHWC)
    float* xpad   = xs + 2097152;          // 2,230,272  (8*66*66*64, NHWC padded)

    k_pool<<<512, 256, 0, stream>>>(x, pooled);
    k_xsproj<<<512, 256, 0, stream>>>(x, refl, tap_w, tap_b, pooled,
                                      gw1, gb1, gw2, gb2,
                                      inp_w, inp_b, xs, xpad);
    k_dwsamp<<<4096, 128, 0, stream>>>(xs, xpad, dw_w, dw_b, ln_g, ln_b,
                                       off_w, off_b, mask_w, mask_b,
                                       outp_w, outp_b, bn1_g, bn1_b, bn1_m, bn1_v,
                                       conv_w, conv_b, bn2_g, bn2_b, bn2_m, bn2_v,
                                       (float*)d_out);
}